// Round 18
// baseline (146.224 us; speedup 1.0000x reference)
//
#include <hip/hip_runtime.h>
#include <stdint.h>

#define NCLS 80
#define MAXB 150
#define BATCH 16
#define NANCH 25200
#define SEGS 4       // candidate-list segments per (image,class) (atomic spread)
#define SEGCAP 512   // per-segment cap; mean fill ~150 -> ~10 sigma margin
#define CAP2 12000   // hard bound: 80 classes * 150 kept max
#define NBINS 411    // score hi-bits (0x3F666666,0x3F800000] -> bins 0..410
#define SELCAP 2048
#define WSEL 256     // nms compact capacity (expected ~155)
#define NREC_ALL 403200  // total records across levels/images (1575 blocks x 256)
#define CPAD 16          // counters padded to one per 64B line (atomic contention fix)

typedef unsigned long long u64;
typedef unsigned int u32;
typedef float f4 __attribute__((ext_vector_type(4)));
typedef f4 f4u __attribute__((aligned(4)));  // 4B-aligned vector load

__device__ __forceinline__ float sigm(float x) { return 1.0f / (1.0f + expf(-x)); }

// reference IoU, exact op order: inter / ((area_i + area_j) - inter + 1e-9)
__device__ __forceinline__ float iou_ref(float4 rb_, float ra, float4 cb, float ca) {
  float ltx = fmaxf(rb_.x, cb.x);
  float lty = fmaxf(rb_.y, cb.y);
  float rbx = fminf(rb_.z, cb.z);
  float rby = fminf(rb_.w, cb.w);
  float iw = fmaxf(rbx - ltx, 0.f);
  float ih = fmaxf(rby - lty, 0.f);
  float inter = iw * ih;
  return inter / (ra + ca - inter + 1e-9f);
}

// -- Pass 1 (fused, block-compacted): 256 records/block ------------------------
__global__ __launch_bounds__(256) void decode_kernel(
    const float* __restrict__ p0, const float* __restrict__ p1,
    const float* __restrict__ p2, float* __restrict__ boxes_ws,
    u64* __restrict__ cand_keys, int* __restrict__ cand_cnt) {
  __shared__ int hcnt;
  __shared__ u32 hW[256];
  __shared__ float hthr[256];
  __shared__ float hcs[256];
  int tid = threadIdx.x;
  if (tid == 0) hcnt = 0;
  __syncthreads();
  int W = blockIdx.x * 256 + tid;  // < 403200 always (grid = 1575 blocks)
  int lvl, b, r;
  if (W < 19200) { lvl = 0; b = W / 1200; r = W - b * 1200; }
  else if (W < 96000) { int V = W - 19200; lvl = 1; b = V / 4800; r = V - b * 4800; }
  else { int V = W - 96000; lvl = 2; b = V / 19200; r = V - b * 19200; }
  const int gtab[3] = {20, 40, 80};
  const float rtab[3] = {32.f, 16.f, 8.f};
  const int nbt[3] = {0, 1200, 6000};
  const float awt[3][3] = {{116.f, 156.f, 373.f}, {30.f, 62.f, 59.f}, {10.f, 16.f, 33.f}};
  const float aht[3][3] = {{90.f, 198.f, 326.f}, {61.f, 45.f, 119.f}, {13.f, 30.f, 23.f}};
  const float* fm = (lvl == 0) ? p0 : ((lvl == 1) ? p1 : p2);
  int g = gtab[lvl];
  const float* p = fm + ((size_t)b * (g * g * 3) + r) * 85;
  float tc = p[4];
  float cs = sigm(tc);  // score<=cs in fp32 -> cs>0.9 is a lossless gate
  if (cs > 0.9f) {
    f4 h = *(const f4u*)p;  // tx,ty,tw,th
    int cell = r / 3, a = r - 3 * cell;
    int yy = cell / g, xx = cell - yy * g;
    float ratio = rtab[lvl];
    float cx = (sigm(h.x) + (float)xx) * ratio;
    float cy = (sigm(h.y) + (float)yy) * ratio;
    float w = expf(h.z) * awt[lvl][a];
    float hh = expf(h.w) * aht[lvl][a];
    int n = nbt[lvl] + r;
    reinterpret_cast<float4*>(boxes_ws)[(size_t)b * NANCH + n] = make_float4(
        cx - w * 0.5f, cy - hh * 0.5f, cx + w * 0.5f, cy + hh * 0.5f);
    // conservative logit threshold: val <= thr ==> fl(cs*sigm(val)) <= 0.9f;
    // margin dominates all fp32 error terms; borderline FPs re-tested exactly.
    float t = 0.9f / cs;
    float ratio2 = t / (1.0f - t);
    float thr = logf(ratio2) - (1e-3f + 4e-7f * ratio2);
    int pos = atomicAdd(&hcnt, 1);  // LDS atomic: per-block, nanoseconds
    hW[pos] = (u32)W;
    hthr[pos] = thr;
    hcs[pos] = cs;
  }
  __syncthreads();
  int H = hcnt;  // ~49 expected
  // ---- phase 2: 240 threads = 12 records x 20 slots, dense hot sweep ----
  int idx = tid / 20, slot = tid - idx * 20;
  if (tid < 240) {
    for (int base = 0; base < H; base += 12) {
      int e = base + idx;
      if (e < H) {
        u32 Wr = hW[e];
        float thr = hthr[e];
        float cs = hcs[e];
        int lv2, b2, r2;
        const float* fm2;
        if (Wr < 19200u) { lv2 = 0; b2 = Wr / 1200u; r2 = Wr - b2 * 1200u; fm2 = p0; }
        else if (Wr < 96000u) { u32 V = Wr - 19200u; lv2 = 1; b2 = V / 4800u; r2 = V - b2 * 4800u; fm2 = p1; }
        else { u32 V = Wr - 96000u; lv2 = 2; b2 = V / 19200u; r2 = V - b2 * 19200u; fm2 = p2; }
        const int lbase[3] = {0, 19200, 96000};
        const float* pr = fm2 + (size_t)(Wr - (u32)lbase[lv2]) * 85;
        f4 v = *(const f4u*)(pr + 5 + 4 * slot);  // 16B class logits, coalesced/row
        u32 n = (u32)nbt[lv2] + (u32)r2;
        u32 nkey = 0xFFFFFFFFu - n;
        int seg = (int)(Wr & (SEGS - 1));
#pragma unroll
        for (int k = 0; k < 4; ++k) {
          if (v[k] > thr) {  // lossless pre-filter (thr conservative)
            float s = cs * sigm(v[k]);  // exact reference expression
            if (s > 0.9f) {
              int c = 4 * slot + k;
              int bc = b2 * NCLS + c;
              int pos = atomicAdd(&cand_cnt[(bc * SEGS + seg) * CPAD], 1);
              if (pos < SEGCAP)  // high = score bits, low = ~anchor
                cand_keys[((size_t)bc * SEGS + seg) * SEGCAP + pos] =
                    ((u64)__float_as_uint(s) << 32) | nkey;
            }
          }
        }
      }
    }
  }
}

// -- Pass 2: 256 threads (4 waves) per (image,class): select + bitmask NMS ------
// All parallel phases split across 4 waves; 5120 waves total (20/CU resident).
__global__ __launch_bounds__(256) void nms_kernel(
    const u64* __restrict__ cand_keys, const int* __restrict__ cand_cnt,
    const float* __restrict__ boxes_ws,
    u64* __restrict__ img_keys, int* __restrict__ img_cnt) {
  __shared__ u64 sel[WSEL + 8];
  __shared__ u64 slot[MAXB];
  __shared__ float4 sbox[MAXB];
  __shared__ float sarea[MAXB];
  __shared__ u32 adjw[MAXB][5];  // adjacency rows: 150-bit masks (5x u32)
  __shared__ u32 hist[NBINS];
  __shared__ u32 svalid[5];
  __shared__ int sT, sCge, nsel, sBase;
  int bc = blockIdx.x;
  int b = bc / NCLS, c = bc - b * NCLS;
  int tid = threadIdx.x;
  int cnt[SEGS];
  int count = 0;
#pragma unroll
  for (int s = 0; s < SEGS; ++s) {
    int v = cand_cnt[(bc * SEGS + s) * CPAD];
    cnt[s] = (v > SEGCAP) ? SEGCAP : v;
    count += cnt[s];
  }
  int target = (count < MAXB) ? count : MAXB;
  const u64* seg_base = cand_keys + (size_t)bc * SEGS * SEGCAP;
  for (int i = tid; i < NBINS; i += 256) hist[i] = 0;
  if (tid < MAXB) slot[tid] = 0;
  for (int i = tid; i < MAXB * 5; i += 256) (&adjw[0][0])[i] = 0;
  if (tid < 5) svalid[tid] = 0;
  if (tid == 0) nsel = 0;
  __syncthreads();
  // ---- histogram of score hi-bits (global read; keys L2-hot) ----
#pragma unroll
  for (int s = 0; s < SEGS; ++s)
    for (int i = tid; i < cnt[s]; i += 256)
      atomicAdd(&hist[((u32)(seg_base[s * SEGCAP + i] >> 32) - 0x3F666000u) >> 12], 1u);
  __syncthreads();
  // ---- wave 0: suffix-scan threshold (lane owns 7-bin chunk) ----
  if (tid < 64) {
    int lane = tid;
    u32 bsum[7];
    u32 csum = 0;
    int chunk = lane * 7;  // 64*7 = 448 >= NBINS
#pragma unroll
    for (int m = 0; m < 7; ++m) {
      int j = chunk + m;
      u32 hv = (j < NBINS) ? hist[j] : 0u;
      bsum[m] = hv;
      csum += hv;
    }
    u32 S = csum;  // inclusive suffix sum over lanes
#pragma unroll
    for (int off = 1; off < 64; off <<= 1) {
      u32 o = __shfl_down(S, off);
      if (lane + off < 64) S += o;
    }
    u32 Snext = S - csum;
    bool win = (target > 0) && (S >= (u32)target) && (Snext < (u32)target);
    u64 wmask = __ballot(win);
    int T = NBINS;
    u32 Cge = 0;
    if (wmask) {
      int Tc = 0;
      u32 Cc = 0;
      if (win) {
        u32 acc = Snext;
#pragma unroll
        for (int m = 6; m >= 0; --m) {
          acc += bsum[m];
          if (acc >= (u32)target) { Tc = chunk + m; Cc = acc; break; }
        }
      }
      int wl = __ffsll(wmask) - 1;
      T = __shfl(Tc, wl);
      Cge = __shfl(Cc, wl);
    }
    if (lane == 0) { sT = T; sCge = (int)Cge; }
  }
  __syncthreads();
  int T = sT;
  // ---- select top-`target` keys into slot[rank] ----
  if (sCge <= WSEL) {
    // compact bins >= T; LDS-atomic positions (order-irrelevant for rank-select)
#pragma unroll
    for (int s = 0; s < SEGS; ++s)
      for (int i = tid; i < cnt[s]; i += 256) {
        u64 k = seg_base[s * SEGCAP + i];
        if ((int)(((u32)(k >> 32) - 0x3F666000u) >> 12) >= T) sel[atomicAdd(&nsel, 1)] = k;
      }
    __syncthreads();
    int C = nsel;
    int C8 = (C + 7) & ~7;
    for (int j = C + tid; j < C8; j += 256) sel[j] = 0;  // pad: 0 never outranks
    __syncthreads();
    for (int i = tid; i < C; i += 256) {  // rank-select (keys unique), 8-deep
      u64 k = sel[i];
      int rank = 0;
      for (int j = 0; j < C8; j += 8) {
        rank += (int)(sel[j] > k) + (int)(sel[j + 1] > k) + (int)(sel[j + 2] > k) +
                (int)(sel[j + 3] > k) + (int)(sel[j + 4] > k) + (int)(sel[j + 5] > k) +
                (int)(sel[j + 6] > k) + (int)(sel[j + 7] > k);
      }
      if (rank < MAXB) slot[rank] = k;
    }
  } else {
    // fallback (pathological bin concentration; never taken on this data)
#pragma unroll
    for (int s = 0; s < SEGS; ++s)
      for (int i = tid; i < cnt[s]; i += 256) {
        u64 k = seg_base[s * SEGCAP + i];
        int rank = 0;
        for (int s2 = 0; s2 < SEGS; ++s2)
          for (int j = 0; j < cnt[s2]; ++j)
            rank += (seg_base[s2 * SEGCAP + j] > k) ? 1 : 0;
        if (rank < MAXB) slot[rank] = k;
      }
  }
  __syncthreads();
  // ---- box gather + valid bits ----
  if (tid < MAXB) {
    u64 k = slot[tid];
    float4 bx = make_float4(0.f, 0.f, 0.f, 0.f);
    float ar = 0.f;
    if (k) {
      int n = (int)(0xFFFFFFFFu - (u32)(k & 0xFFFFFFFFu));
      bx = reinterpret_cast<const float4*>(boxes_ws)[(size_t)b * NANCH + n];
      ar = (bx.z - bx.x) * (bx.w - bx.y);
      atomicOr(&svalid[tid >> 5], 1u << (tid & 31));
    }
    sbox[tid] = bx;
    sarea[tid] = ar;
  }
  __syncthreads();
  // ---- adjacency build: balanced strided sweep of the (i<j) cell square ----
  // bit j set in row i iff iou(i,j) > 0.1 (invalid boxes give iou==0 -> no bit)
  for (int q = tid; q < MAXB * MAXB; q += 256) {
    int i = q / MAXB, j = q - i * MAXB;
    if (i < j && j < target) {
      if (iou_ref(sbox[i], sarea[i], sbox[j], sarea[j]) > 0.1f)
        atomicOr(&adjw[i][j >> 5], 1u << (j & 31));
    }
  }
  __syncthreads();
  // ---- serial greedy scan: register-only, redundant in every thread ----
  u32 sup0 = 0, sup1 = 0, sup2 = 0, sup3 = 0, sup4 = 0;
  u32 va0 = svalid[0], va1 = svalid[1], va2 = svalid[2], va3 = svalid[3],
      va4 = svalid[4];
  for (int i = 0; i < target; ++i) {
    u32 bit = 1u << (i & 31);
    int iw = i >> 5;
    u32 viw = (iw == 0) ? va0 : ((iw == 1) ? va1 : ((iw == 2) ? va2 : ((iw == 3) ? va3 : va4)));
    u32 siw = (iw == 0) ? sup0 : ((iw == 1) ? sup1 : ((iw == 2) ? sup2 : ((iw == 3) ? sup3 : sup4)));
    if (viw & ~siw & bit) {
      sup0 |= adjw[i][0];
      sup1 |= adjw[i][1];
      sup2 |= adjw[i][2];
      sup3 |= adjw[i][3];
      sup4 |= adjw[i][4];
    }
  }
  u32 kp0 = va0 & ~sup0, kp1 = va1 & ~sup1, kp2 = va2 & ~sup2, kp3 = va3 & ~sup3,
      kp4 = va4 & ~sup4;
  int total = (int)(__popc(kp0) + __popc(kp1) + __popc(kp2) + __popc(kp3) + __popc(kp4));
  if (tid == 0 && total > 0) sBase = atomicAdd(&img_cnt[b * CPAD], total);
  __syncthreads();
  // ---- append kept entries in rank order (prefix of keep bits) ----
  if (tid < MAXB) {
    int w = tid >> 5, bi = tid & 31;
    u32 kw = (w == 0) ? kp0 : ((w == 1) ? kp1 : ((w == 2) ? kp2 : ((w == 3) ? kp3 : kp4)));
    if ((kw >> bi) & 1) {
      int pos = 0;
      if (w > 0) pos += __popc(kp0);
      if (w > 1) pos += __popc(kp1);
      if (w > 2) pos += __popc(kp2);
      if (w > 3) pos += __popc(kp3);
      pos += __popc(kw & ((1u << bi) - 1u));
      u64 k = slot[tid];
      u32 e = (u32)(c * MAXB + tid);
      u32 anchor = 0xFFFFFFFFu - (u32)(k & 0xFFFFFFFFu);
      // key = [score:32][(0x3FFF - e):14][anchor:15]  (unique per entry)
      img_keys[(size_t)b * CAP2 + sBase + pos] =
          ((k >> 32) << 32) | ((u64)(0x3FFFu - e) << 15) | anchor;
    }
  }
}

// ---------------- Pass 3: per-image top-150 via exact histogram select ----------
__global__ __launch_bounds__(1024) void final_kernel(
    const u64* __restrict__ img_keys, const int* __restrict__ img_cnt,
    const float* __restrict__ boxes_ws, float* __restrict__ out) {
  __shared__ u32 hist[NBINS];
  __shared__ u64 sel[SELCAP];   // 16 KB
  __shared__ u64 slot[MAXB];
  __shared__ int sT, sCge, nsel;
  int b = blockIdx.x, tid = threadIdx.x;
  int L = img_cnt[b * CPAD];
  if (L > CAP2) L = CAP2;
  const u64* src = img_keys + (size_t)b * CAP2;
  for (int i = tid; i < NBINS; i += 1024) hist[i] = 0;
  if (tid < MAXB) slot[tid] = 0;
  if (tid == 0) nsel = 0;
  __syncthreads();
  for (int i = tid; i < L; i += 1024) {
    u32 hi = (u32)(src[i] >> 32);
    atomicAdd(&hist[(hi - 0x3F666000u) >> 12], 1u);
  }
  __syncthreads();
  if (tid < 64) {  // wave-parallel suffix-scan threshold
    int lane = tid;
    int target = (L < MAXB) ? L : MAXB;
    u32 bsum[7];
    u32 csum = 0;
    int chunk = lane * 7;
#pragma unroll
    for (int m = 0; m < 7; ++m) {
      int j = chunk + m;
      u32 hv = (j < NBINS) ? hist[j] : 0u;
      bsum[m] = hv;
      csum += hv;
    }
    u32 S = csum;
#pragma unroll
    for (int off = 1; off < 64; off <<= 1) {
      u32 o = __shfl_down(S, off);
      if (lane + off < 64) S += o;
    }
    u32 Snext = S - csum;
    bool win = (target > 0) && (S >= (u32)target) && (Snext < (u32)target);
    u64 wmask = __ballot(win);
    int T = NBINS;
    u32 Cge = 0;
    if (wmask) {
      int Tc = 0;
      u32 Cc = 0;
      if (win) {
        u32 acc = Snext;
#pragma unroll
        for (int m = 6; m >= 0; --m) {
          acc += bsum[m];
          if (acc >= (u32)target) { Tc = chunk + m; Cc = acc; break; }
        }
      }
      int wl = __ffsll(wmask) - 1;
      T = __shfl(Tc, wl);
      Cge = __shfl(Cc, wl);
    }
    if (lane == 0) { sT = T; sCge = (int)Cge; }
  }
  __syncthreads();
  int T = sT, cge = sCge;
  float* ob = out;                      // [B][150][4]
  float* osc = out + BATCH * MAXB * 4;  // [B][150]
  float* olb = out + BATCH * MAXB * 5;  // [B][150] labels (as float)
  if (cge <= SELCAP) {
    for (int i = tid; i < L; i += 1024) {
      u64 k = src[i];
      if ((int)(((u32)(k >> 32) - 0x3F666000u) >> 12) >= T) {
        int pos = atomicAdd(&nsel, 1);
        sel[pos] = k;
      }
    }
    __syncthreads();
    int C = nsel;
    for (int i = tid; i < C; i += 1024) {
      u64 k = sel[i];
      int rank = 0;
      for (int j = 0; j < C; ++j) rank += (sel[j] > k) ? 1 : 0;  // LDS broadcast
      if (rank < MAXB) slot[rank] = k;
    }
    __syncthreads();
  } else {
    for (int i = tid; i < L; i += 1024) {
      u64 k = src[i];
      int rank = 0;
      for (int j = 0; j < L; ++j) rank += (src[j] > k) ? 1 : 0;
      if (rank < MAXB) slot[rank] = k;
    }
    __syncthreads();
  }
  if (tid < MAXB) {
    u64 k = slot[tid];
    float* q = ob + ((size_t)b * MAXB + tid) * 4;
    if (k) {
      u32 e = 0x3FFFu - (u32)((k >> 15) & 0x3FFFu);
      int c = (int)(e / MAXB);
      int anchor = (int)(k & 0x7FFFu);
      float4 bx = reinterpret_cast<const float4*>(boxes_ws)[(size_t)b * NANCH + anchor];
      q[0] = bx.x; q[1] = bx.y; q[2] = bx.z; q[3] = bx.w;
      osc[(size_t)b * MAXB + tid] = __uint_as_float((u32)(k >> 32));
      olb[(size_t)b * MAXB + tid] = (float)c;
    } else {
      q[0] = q[1] = q[2] = q[3] = -1.f;
      osc[(size_t)b * MAXB + tid] = -1.f;
      olb[(size_t)b * MAXB + tid] = -1.f;
    }
  }
}

extern "C" void kernel_launch(void* const* d_in, const int* in_sizes, int n_in,
                              void* d_out, int out_size, void* d_ws, size_t ws_size,
                              hipStream_t stream) {
  (void)in_sizes; (void)n_in; (void)out_size; (void)ws_size;
  const float* p0 = (const float*)d_in[0];  // [16,20,20,255] anchors[6:9]
  const float* p1 = (const float*)d_in[1];  // [16,40,40,255] anchors[3:6]
  const float* p2 = (const float*)d_in[2];  // [16,80,80,255] anchors[0:3]
  char* ws = (char*)d_ws;
  float* boxes_ws = (float*)ws;              // 16*25200*16 B          -> 6,451,200
  int* cand_cnt = (int*)(ws + 6451200);      // 1280*4*16 i32 (padded) -> 6,778,880
  int* img_cnt = (int*)(ws + 6778880);       // 16*16 i32 (padded)     -> 6,779,904
  u64* cand_keys = (u64*)(ws + 6779904);     // 1280*4*512 u64         -> 27,751,424
  u64* img_keys = (u64*)(ws + 27751424);     // 16*12000 u64           -> 29,287,424

  hipMemsetAsync(cand_cnt, 0, (NCLS * BATCH * SEGS + BATCH) * CPAD * sizeof(int),
                 stream);

  decode_kernel<<<NREC_ALL / 256, 256, 0, stream>>>(
      p0, p1, p2, boxes_ws, cand_keys, cand_cnt);
  nms_kernel<<<BATCH * NCLS, 256, 0, stream>>>(cand_keys, cand_cnt, boxes_ws,
                                               img_keys, img_cnt);
  final_kernel<<<BATCH, 1024, 0, stream>>>(img_keys, img_cnt, boxes_ws, (float*)d_out);
}

// Round 19
// 111.330 us; speedup vs baseline: 1.3134x; 1.3134x over previous
//
#include <hip/hip_runtime.h>
#include <stdint.h>

#define NCLS 80
#define MAXB 150
#define BATCH 16
#define NANCH 25200
#define SEGS 4       // candidate-list segments per (image,class) (atomic spread)
#define SEGCAP 512   // per-segment cap; mean fill ~150 -> ~10 sigma margin
#define CAP2 12000   // hard bound: 80 classes * 150 kept max
#define NBINS 411    // score hi-bits (0x3F666666,0x3F800000] -> bins 0..410
#define SELCAP 2048
#define WSEL 256     // nms compact capacity (expected ~155)
#define NREC_ALL 403200  // total records across levels/images (1575 blocks x 256)
#define CPAD 16          // counters padded to one per 64B line (atomic contention fix)
#define NWORDS 5         // 150-bit masks per adjacency row

typedef unsigned long long u64;
typedef unsigned int u32;
typedef float f4 __attribute__((ext_vector_type(4)));
typedef f4 f4u __attribute__((aligned(4)));  // 4B-aligned vector load

__device__ __forceinline__ float sigm(float x) { return 1.0f / (1.0f + expf(-x)); }

// reference IoU, exact op order: inter / ((area_i + area_j) - inter + 1e-9)
__device__ __forceinline__ float iou_ref(float4 rb_, float ra, float4 cb, float ca) {
  float ltx = fmaxf(rb_.x, cb.x);
  float lty = fmaxf(rb_.y, cb.y);
  float rbx = fminf(rb_.z, cb.z);
  float rby = fminf(rb_.w, cb.w);
  float iw = fmaxf(rbx - ltx, 0.f);
  float ih = fmaxf(rby - lty, 0.f);
  float inter = iw * ih;
  return inter / (ra + ca - inter + 1e-9f);
}

// -- Pass 1 (fused, block-compacted): 256 records/block ------------------------
__global__ __launch_bounds__(256) void decode_kernel(
    const float* __restrict__ p0, const float* __restrict__ p1,
    const float* __restrict__ p2, float* __restrict__ boxes_ws,
    u64* __restrict__ cand_keys, int* __restrict__ cand_cnt) {
  __shared__ int hcnt;
  __shared__ u32 hW[256];
  __shared__ float hthr[256];
  __shared__ float hcs[256];
  int tid = threadIdx.x;
  if (tid == 0) hcnt = 0;
  __syncthreads();
  int W = blockIdx.x * 256 + tid;  // < 403200 always (grid = 1575 blocks)
  int lvl, b, r;
  if (W < 19200) { lvl = 0; b = W / 1200; r = W - b * 1200; }
  else if (W < 96000) { int V = W - 19200; lvl = 1; b = V / 4800; r = V - b * 4800; }
  else { int V = W - 96000; lvl = 2; b = V / 19200; r = V - b * 19200; }
  const int gtab[3] = {20, 40, 80};
  const float rtab[3] = {32.f, 16.f, 8.f};
  const int nbt[3] = {0, 1200, 6000};
  const float awt[3][3] = {{116.f, 156.f, 373.f}, {30.f, 62.f, 59.f}, {10.f, 16.f, 33.f}};
  const float aht[3][3] = {{90.f, 198.f, 326.f}, {61.f, 45.f, 119.f}, {13.f, 30.f, 23.f}};
  const float* fm = (lvl == 0) ? p0 : ((lvl == 1) ? p1 : p2);
  int g = gtab[lvl];
  const float* p = fm + ((size_t)b * (g * g * 3) + r) * 85;
  f4 h = *(const f4u*)p;  // bytes 0-15: same 64B line as conf -> free
  float tc = p[4];
  float cs = sigm(tc);  // score<=cs in fp32 -> cs>0.9 is a lossless gate
  if (cs > 0.9f) {
    int cell = r / 3, a = r - 3 * cell;
    int yy = cell / g, xx = cell - yy * g;
    float ratio = rtab[lvl];
    float cx = (sigm(h.x) + (float)xx) * ratio;
    float cy = (sigm(h.y) + (float)yy) * ratio;
    float w = expf(h.z) * awt[lvl][a];
    float hh = expf(h.w) * aht[lvl][a];
    int n = nbt[lvl] + r;
    reinterpret_cast<float4*>(boxes_ws)[(size_t)b * NANCH + n] = make_float4(
        cx - w * 0.5f, cy - hh * 0.5f, cx + w * 0.5f, cy + hh * 0.5f);
    // conservative logit threshold: val <= thr ==> fl(cs*sigm(val)) <= 0.9f;
    // margin dominates all fp32 error terms; borderline FPs re-tested exactly.
    float t = 0.9f / cs;
    float ratio2 = t / (1.0f - t);
    float thr = logf(ratio2) - (1e-3f + 4e-7f * ratio2);
    int pos = atomicAdd(&hcnt, 1);  // LDS atomic: per-block, nanoseconds
    hW[pos] = (u32)W;
    hthr[pos] = thr;
    hcs[pos] = cs;
  }
  __syncthreads();
  int H = hcnt;  // ~49 expected
  // ---- phase 2: 240 threads = 12 records x 20 slots, dense hot sweep ----
  int idx = tid / 20, slot = tid - idx * 20;
  if (tid < 240) {
    for (int base = 0; base < H; base += 12) {
      int e = base + idx;
      if (e < H) {
        u32 Wr = hW[e];
        float thr = hthr[e];
        float cs2 = hcs[e];
        int lv2, b2, r2;
        const float* fm2;
        if (Wr < 19200u) { lv2 = 0; b2 = Wr / 1200u; r2 = Wr - b2 * 1200u; fm2 = p0; }
        else if (Wr < 96000u) { u32 V = Wr - 19200u; lv2 = 1; b2 = V / 4800u; r2 = V - b2 * 4800u; fm2 = p1; }
        else { u32 V = Wr - 96000u; lv2 = 2; b2 = V / 19200u; r2 = V - b2 * 19200u; fm2 = p2; }
        const int lbase[3] = {0, 19200, 96000};
        const float* pr = fm2 + (size_t)(Wr - (u32)lbase[lv2]) * 85;
        f4 v = *(const f4u*)(pr + 5 + 4 * slot);  // 16B class logits, coalesced/row
        u32 n = (u32)nbt[lv2] + (u32)r2;
        u32 nkey = 0xFFFFFFFFu - n;
        int seg = (int)(Wr & (SEGS - 1));
#pragma unroll
        for (int k = 0; k < 4; ++k) {
          if (v[k] > thr) {  // lossless pre-filter (thr conservative)
            float s = cs2 * sigm(v[k]);  // exact reference expression
            if (s > 0.9f) {
              int c = 4 * slot + k;
              int bc = b2 * NCLS + c;
              int pos = atomicAdd(&cand_cnt[(bc * SEGS + seg) * CPAD], 1);
              if (pos < SEGCAP)  // high = score bits, low = ~anchor
                cand_keys[((size_t)bc * SEGS + seg) * SEGCAP + pos] =
                    ((u64)__float_as_uint(s) << 32) | nkey;
            }
          }
        }
      }
    }
  }
}

// -- Pass 2: 256 threads per (image,class): select + word-owner bitmask NMS -----
__global__ __launch_bounds__(256) void nms_kernel(
    const u64* __restrict__ cand_keys, const int* __restrict__ cand_cnt,
    const float* __restrict__ boxes_ws,
    u64* __restrict__ img_keys, int* __restrict__ img_cnt) {
  __shared__ u64 sel[WSEL + 8];
  __shared__ u64 slot[MAXB];
  __shared__ float4 sbox[MAXB];
  __shared__ float sarea[MAXB];
  __shared__ u32 adjw[MAXB][NWORDS];  // adjacency rows (each word written once)
  __shared__ u32 hist[NBINS];
  __shared__ u32 svalid[NWORDS];
  __shared__ u32 skp[NWORDS];
  __shared__ u32 anyadj;
  __shared__ int sT, sCge, nsel, sBase;
  int bc = blockIdx.x;
  int b = bc / NCLS, c = bc - b * NCLS;
  int tid = threadIdx.x;
  int cnt[SEGS];
  int count = 0;
#pragma unroll
  for (int s = 0; s < SEGS; ++s) {
    int v = cand_cnt[(bc * SEGS + s) * CPAD];
    cnt[s] = (v > SEGCAP) ? SEGCAP : v;
    count += cnt[s];
  }
  int target = (count < MAXB) ? count : MAXB;
  const u64* seg_base = cand_keys + (size_t)bc * SEGS * SEGCAP;
  for (int i = tid; i < NBINS; i += 256) hist[i] = 0;
  if (tid < MAXB) slot[tid] = 0;
  if (tid < NWORDS) svalid[tid] = 0;
  if (tid == 0) { nsel = 0; anyadj = 0; }
  __syncthreads();
  // ---- histogram of score hi-bits (global read; keys L2-hot) ----
#pragma unroll
  for (int s = 0; s < SEGS; ++s)
    for (int i = tid; i < cnt[s]; i += 256)
      atomicAdd(&hist[((u32)(seg_base[s * SEGCAP + i] >> 32) - 0x3F666000u) >> 12], 1u);
  __syncthreads();
  // ---- wave 0: suffix-scan threshold (lane owns 7-bin chunk) ----
  if (tid < 64) {
    int lane = tid;
    u32 bsum[7];
    u32 csum = 0;
    int chunk = lane * 7;  // 64*7 = 448 >= NBINS
#pragma unroll
    for (int m = 0; m < 7; ++m) {
      int j = chunk + m;
      u32 hv = (j < NBINS) ? hist[j] : 0u;
      bsum[m] = hv;
      csum += hv;
    }
    u32 S = csum;  // inclusive suffix sum over lanes
#pragma unroll
    for (int off = 1; off < 64; off <<= 1) {
      u32 o = __shfl_down(S, off);
      if (lane + off < 64) S += o;
    }
    u32 Snext = S - csum;
    bool win = (target > 0) && (S >= (u32)target) && (Snext < (u32)target);
    u64 wmask = __ballot(win);
    int T = NBINS;
    u32 Cge = 0;
    if (wmask) {
      int Tc = 0;
      u32 Cc = 0;
      if (win) {
        u32 acc = Snext;
#pragma unroll
        for (int m = 6; m >= 0; --m) {
          acc += bsum[m];
          if (acc >= (u32)target) { Tc = chunk + m; Cc = acc; break; }
        }
      }
      int wl = __ffsll(wmask) - 1;
      T = __shfl(Tc, wl);
      Cge = __shfl(Cc, wl);
    }
    if (lane == 0) { sT = T; sCge = (int)Cge; }
  }
  __syncthreads();
  int T = sT;
  // ---- select top-`target` keys into slot[rank] ----
  if (sCge <= WSEL) {
    // compact bins >= T; LDS-atomic positions (order-irrelevant for rank-select)
#pragma unroll
    for (int s = 0; s < SEGS; ++s)
      for (int i = tid; i < cnt[s]; i += 256) {
        u64 k = seg_base[s * SEGCAP + i];
        if ((int)(((u32)(k >> 32) - 0x3F666000u) >> 12) >= T) sel[atomicAdd(&nsel, 1)] = k;
      }
    __syncthreads();
    int C = nsel;
    int C8 = (C + 7) & ~7;
    for (int j = C + tid; j < C8; j += 256) sel[j] = 0;  // pad: 0 never outranks
    __syncthreads();
    for (int i = tid; i < C; i += 256) {  // rank-select (keys unique), 8-deep
      u64 k = sel[i];
      int rank = 0;
      for (int j = 0; j < C8; j += 8) {
        rank += (int)(sel[j] > k) + (int)(sel[j + 1] > k) + (int)(sel[j + 2] > k) +
                (int)(sel[j + 3] > k) + (int)(sel[j + 4] > k) + (int)(sel[j + 5] > k) +
                (int)(sel[j + 6] > k) + (int)(sel[j + 7] > k);
      }
      if (rank < MAXB) slot[rank] = k;
    }
  } else {
    // fallback (pathological bin concentration; never taken on this data)
#pragma unroll
    for (int s = 0; s < SEGS; ++s)
      for (int i = tid; i < cnt[s]; i += 256) {
        u64 k = seg_base[s * SEGCAP + i];
        int rank = 0;
        for (int s2 = 0; s2 < SEGS; ++s2)
          for (int j = 0; j < cnt[s2]; ++j)
            rank += (seg_base[s2 * SEGCAP + j] > k) ? 1 : 0;
        if (rank < MAXB) slot[rank] = k;
      }
  }
  __syncthreads();
  // ---- box gather + valid bits ----
  if (tid < MAXB) {
    u64 k = slot[tid];
    float4 bx = make_float4(0.f, 0.f, 0.f, 0.f);
    float ar = 0.f;
    if (k) {
      int n = (int)(0xFFFFFFFFu - (u32)(k & 0xFFFFFFFFu));
      bx = reinterpret_cast<const float4*>(boxes_ws)[(size_t)b * NANCH + n];
      ar = (bx.z - bx.x) * (bx.w - bx.y);
      atomicOr(&svalid[tid >> 5], 1u << (tid & 31));
    }
    sbox[tid] = bx;
    sarea[tid] = ar;
  }
  __syncthreads();
  // ---- adjacency build: thread OWNS whole u32 words (no atomics, no per-cell div)
  // word (i,w): bits j in [32w,32w+32) ∩ (i, target) with iou(i,j) > 0.1.
  // invalid row/col boxes are all-zero -> iou==0 -> no bits (no validity check).
  for (int wq = tid; wq < MAXB * NWORDS; wq += 256) {
    int i = wq / NWORDS, w = wq - i * NWORDS;
    int jlo = 32 * w;
    if (jlo < i + 1) jlo = i + 1;
    int jhi = 32 * w + 32;
    if (jhi > target) jhi = target;
    u32 bits = 0;
    if (jlo < jhi) {
      float4 bi = sbox[i];
      float ai = sarea[i];
      for (int j = jlo; j < jhi; ++j)
        if (iou_ref(bi, ai, sbox[j], sarea[j]) > 0.1f) bits |= 1u << (j & 31);
    }
    adjw[i][w] = bits;
    if (bits) atomicOr(&anyadj, 1u);
  }
  __syncthreads();
  // ---- greedy scan: wave 0 only; lean 5-body unrolled, loads unconditional ----
  if (tid < 64) {
    u32 va0 = svalid[0], va1 = svalid[1], va2 = svalid[2], va3 = svalid[3],
        va4 = svalid[4];
    u32 sup0 = 0, sup1 = 0, sup2 = 0, sup3 = 0, sup4 = 0;
    if (anyadj) {
#define SCAN_WORD(W0, SUPW, VAW)                                          \
  {                                                                       \
    int i0 = 32 * (W0);                                                   \
    int ie = target - i0;                                                 \
    if (ie > 32) ie = 32;                                                 \
    for (int ii = 0; ii < ie; ++ii) {                                     \
      int i = i0 + ii;                                                    \
      u32 a0 = adjw[i][0], a1 = adjw[i][1], a2 = adjw[i][2],              \
          a3 = adjw[i][3], a4 = adjw[i][4];                               \
      u32 take = ((VAW) & ~(SUPW) & (1u << ii)) ? 0xFFFFFFFFu : 0u;       \
      sup0 |= a0 & take; sup1 |= a1 & take; sup2 |= a2 & take;            \
      sup3 |= a3 & take; sup4 |= a4 & take;                               \
    }                                                                     \
  }
      SCAN_WORD(0, sup0, va0)
      SCAN_WORD(1, sup1, va1)
      SCAN_WORD(2, sup2, va2)
      SCAN_WORD(3, sup3, va3)
      SCAN_WORD(4, sup4, va4)
#undef SCAN_WORD
    }
    u32 kp0 = va0 & ~sup0, kp1 = va1 & ~sup1, kp2 = va2 & ~sup2,
        kp3 = va3 & ~sup3, kp4 = va4 & ~sup4;
    if (tid == 0) {
      skp[0] = kp0; skp[1] = kp1; skp[2] = kp2; skp[3] = kp3; skp[4] = kp4;
      int total = (int)(__popc(kp0) + __popc(kp1) + __popc(kp2) + __popc(kp3) +
                        __popc(kp4));
      sBase = (total > 0) ? atomicAdd(&img_cnt[b * CPAD], total) : 0;
    }
  }
  __syncthreads();
  // ---- append kept entries in rank order (prefix of keep bits) ----
  if (tid < MAXB) {
    int w = tid >> 5, bi = tid & 31;
    u32 kw = skp[w];
    if ((kw >> bi) & 1) {
      int pos = 0;
      for (int ww = 0; ww < w; ++ww) pos += __popc(skp[ww]);
      pos += __popc(kw & ((1u << bi) - 1u));
      u64 k = slot[tid];
      u32 e = (u32)(c * MAXB + tid);
      u32 anchor = 0xFFFFFFFFu - (u32)(k & 0xFFFFFFFFu);
      // key = [score:32][(0x3FFF - e):14][anchor:15]  (unique per entry)
      img_keys[(size_t)b * CAP2 + sBase + pos] =
          ((k >> 32) << 32) | ((u64)(0x3FFFu - e) << 15) | anchor;
    }
  }
}

// ---------------- Pass 3: per-image top-150 via exact histogram select ----------
__global__ __launch_bounds__(1024) void final_kernel(
    const u64* __restrict__ img_keys, const int* __restrict__ img_cnt,
    const float* __restrict__ boxes_ws, float* __restrict__ out) {
  __shared__ u32 hist[NBINS];
  __shared__ u64 sel[SELCAP];   // 16 KB
  __shared__ u64 slot[MAXB];
  __shared__ int sT, sCge, nsel;
  int b = blockIdx.x, tid = threadIdx.x;
  int L = img_cnt[b * CPAD];
  if (L > CAP2) L = CAP2;
  const u64* src = img_keys + (size_t)b * CAP2;
  for (int i = tid; i < NBINS; i += 1024) hist[i] = 0;
  if (tid < MAXB) slot[tid] = 0;
  if (tid == 0) nsel = 0;
  __syncthreads();
  for (int i = tid; i < L; i += 1024) {
    u32 hi = (u32)(src[i] >> 32);
    atomicAdd(&hist[(hi - 0x3F666000u) >> 12], 1u);
  }
  __syncthreads();
  if (tid < 64) {  // wave-parallel suffix-scan threshold
    int lane = tid;
    int target = (L < MAXB) ? L : MAXB;
    u32 bsum[7];
    u32 csum = 0;
    int chunk = lane * 7;
#pragma unroll
    for (int m = 0; m < 7; ++m) {
      int j = chunk + m;
      u32 hv = (j < NBINS) ? hist[j] : 0u;
      bsum[m] = hv;
      csum += hv;
    }
    u32 S = csum;
#pragma unroll
    for (int off = 1; off < 64; off <<= 1) {
      u32 o = __shfl_down(S, off);
      if (lane + off < 64) S += o;
    }
    u32 Snext = S - csum;
    bool win = (target > 0) && (S >= (u32)target) && (Snext < (u32)target);
    u64 wmask = __ballot(win);
    int T = NBINS;
    u32 Cge = 0;
    if (wmask) {
      int Tc = 0;
      u32 Cc = 0;
      if (win) {
        u32 acc = Snext;
#pragma unroll
        for (int m = 6; m >= 0; --m) {
          acc += bsum[m];
          if (acc >= (u32)target) { Tc = chunk + m; Cc = acc; break; }
        }
      }
      int wl = __ffsll(wmask) - 1;
      T = __shfl(Tc, wl);
      Cge = __shfl(Cc, wl);
    }
    if (lane == 0) { sT = T; sCge = (int)Cge; }
  }
  __syncthreads();
  int T = sT, cge = sCge;
  float* ob = out;                      // [B][150][4]
  float* osc = out + BATCH * MAXB * 4;  // [B][150]
  float* olb = out + BATCH * MAXB * 5;  // [B][150] labels (as float)
  if (cge <= SELCAP) {
    for (int i = tid; i < L; i += 1024) {
      u64 k = src[i];
      if ((int)(((u32)(k >> 32) - 0x3F666000u) >> 12) >= T) {
        int pos = atomicAdd(&nsel, 1);
        sel[pos] = k;
      }
    }
    __syncthreads();
    int C = nsel;
    for (int i = tid; i < C; i += 1024) {
      u64 k = sel[i];
      int rank = 0;
      for (int j = 0; j < C; ++j) rank += (sel[j] > k) ? 1 : 0;  // LDS broadcast
      if (rank < MAXB) slot[rank] = k;
    }
    __syncthreads();
  } else {
    for (int i = tid; i < L; i += 1024) {
      u64 k = src[i];
      int rank = 0;
      for (int j = 0; j < L; ++j) rank += (src[j] > k) ? 1 : 0;
      if (rank < MAXB) slot[rank] = k;
    }
    __syncthreads();
  }
  if (tid < MAXB) {
    u64 k = slot[tid];
    float* q = ob + ((size_t)b * MAXB + tid) * 4;
    if (k) {
      u32 e = 0x3FFFu - (u32)((k >> 15) & 0x3FFFu);
      int c = (int)(e / MAXB);
      int anchor = (int)(k & 0x7FFFu);
      float4 bx = reinterpret_cast<const float4*>(boxes_ws)[(size_t)b * NANCH + anchor];
      q[0] = bx.x; q[1] = bx.y; q[2] = bx.z; q[3] = bx.w;
      osc[(size_t)b * MAXB + tid] = __uint_as_float((u32)(k >> 32));
      olb[(size_t)b * MAXB + tid] = (float)c;
    } else {
      q[0] = q[1] = q[2] = q[3] = -1.f;
      osc[(size_t)b * MAXB + tid] = -1.f;
      olb[(size_t)b * MAXB + tid] = -1.f;
    }
  }
}

extern "C" void kernel_launch(void* const* d_in, const int* in_sizes, int n_in,
                              void* d_out, int out_size, void* d_ws, size_t ws_size,
                              hipStream_t stream) {
  (void)in_sizes; (void)n_in; (void)out_size; (void)ws_size;
  const float* p0 = (const float*)d_in[0];  // [16,20,20,255] anchors[6:9]
  const float* p1 = (const float*)d_in[1];  // [16,40,40,255] anchors[3:6]
  const float* p2 = (const float*)d_in[2];  // [16,80,80,255] anchors[0:3]
  char* ws = (char*)d_ws;
  float* boxes_ws = (float*)ws;              // 16*25200*16 B          -> 6,451,200
  int* cand_cnt = (int*)(ws + 6451200);      // 1280*4*16 i32 (padded) -> 6,778,880
  int* img_cnt = (int*)(ws + 6778880);       // 16*16 i32 (padded)     -> 6,779,904
  u64* cand_keys = (u64*)(ws + 6779904);     // 1280*4*512 u64         -> 27,751,424
  u64* img_keys = (u64*)(ws + 27751424);     // 16*12000 u64           -> 29,287,424

  hipMemsetAsync(cand_cnt, 0, (NCLS * BATCH * SEGS + BATCH) * CPAD * sizeof(int),
                 stream);

  decode_kernel<<<NREC_ALL / 256, 256, 0, stream>>>(
      p0, p1, p2, boxes_ws, cand_keys, cand_cnt);
  nms_kernel<<<BATCH * NCLS, 256, 0, stream>>>(cand_keys, cand_cnt, boxes_ws,
                                               img_keys, img_cnt);
  final_kernel<<<BATCH, 1024, 0, stream>>>(img_keys, img_cnt, boxes_ws, (float*)d_out);
}